// Round 2
// 612.947 us; speedup vs baseline: 1.0251x; 1.0251x over previous
//
#include <hip/hip_runtime.h>
#include <hip/hip_bf16.h>
#include <math.h>

#define N_TOK 131072
#define DIM 256
#define HID 512
#define NE 16
#define CAP 18023

typedef __bf16 bf16_t;
typedef __bf16 bf16x4 __attribute__((ext_vector_type(4)));
typedef __bf16 bf16x8 __attribute__((ext_vector_type(8)));
typedef float floatx4 __attribute__((ext_vector_type(4)));
typedef double doublex4 __attribute__((ext_vector_type(4)));

// ---------------------------------------------------------------------------
// Workspace layout (bytes):
//   0        : int   cnt[16*16]   (one counter per 64B line: cnt[e*16])
//   1024     : float imp[16*16]   (padded: imp[e*16])
//   2048     : float ent[1]
//   4096     : int   tok_list[16*CAP] (1153472 B)
//   1157568  : float sc_list[16*CAP]  (1153472 B)
//   2311168  : bf16  W1T[16][512][256] (4 MiB)   W1T[e][n][k] = W1[e][k][n]
//   6505472  : bf16  W2T[16][256][512] (4 MiB)   W2T[e][d][h] = W2[e][h][d]
//   10699776 : int   inv[N][2]  (1 MiB)  slot id e*CAP+pos per pick, -1 if dropped
//   11748352 : bf16  y_buf[16][CAP][256] (147.6 MB)  gate-scaled expert outputs
// total ~152 MB. If ws_size is smaller, fall back to atomic combine.
// ---------------------------------------------------------------------------
#define OFF_CNT 0
#define OFF_IMP 1024
#define OFF_ENT 2048
#define OFF_TOK 4096
#define OFF_SC 1157568
#define OFF_W1T 2311168
#define OFF_W2T 6505472
#define OFF_INV 10699776
#define OFF_Y 11748352
#define WS_NEED (11748352UL + (size_t)NE * CAP * DIM * 2)

// ---------------- init stats (gather path: no output zeroing needed) ----------------
__global__ void k_init(int* __restrict__ cnt, float* __restrict__ imp,
                       float* __restrict__ ent) {
  if (threadIdx.x < NE) { cnt[threadIdx.x * 16] = 0; imp[threadIdx.x * 16] = 0.f; }
  if (threadIdx.x == NE) ent[0] = 0.f;
}

// ---------------- zero output (atomic-fallback path only) ----------------
__global__ void k_zero_out(float* __restrict__ out) {
  const int nthreads = 2048 * 256;
  int tid = blockIdx.x * 256 + threadIdx.x;
  float4* o4 = (float4*)out;
  float4 z = make_float4(0.f, 0.f, 0.f, 0.f);
#pragma unroll
  for (int j = 0; j < 16; j++) o4[(size_t)j * nthreads + tid] = z;
}

// ---------------- per-expert weight transpose + bf16 cast ----------------
// src: [E][R][C] f32 -> dst: [E][C][R] bf16
__global__ void k_transpose(const float* __restrict__ src, bf16_t* __restrict__ dst,
                            int R, int C) {
  __shared__ float tile[32][33];
  int e = blockIdx.z;
  int c0 = blockIdx.x * 32;
  int r0 = blockIdx.y * 32;
  const float* s = src + (size_t)e * R * C;
  bf16_t* d = dst + (size_t)e * R * C;
  int tx = threadIdx.x, ty = threadIdx.y;  // block (32,8)
#pragma unroll
  for (int i = 0; i < 4; i++)
    tile[ty + i * 8][tx] = s[(size_t)(r0 + ty + i * 8) * C + (c0 + tx)];
  __syncthreads();
#pragma unroll
  for (int i = 0; i < 4; i++)
    d[(size_t)(c0 + ty + i * 8) * R + (r0 + tx)] = (bf16_t)tile[tx][ty + i * 8];
}

// ---------------- router: fp64 logits, top-2, gates, stats, inverse map ----------------
__launch_bounds__(256, 2)
__global__ void k_router(const float* __restrict__ ctx, const float* __restrict__ Wg,
                         const float* __restrict__ bg, int* __restrict__ cnt,
                         int* __restrict__ tok_list, float* __restrict__ sc_list,
                         int* __restrict__ inv,
                         float* __restrict__ imp, float* __restrict__ ent) {
  __shared__ __align__(32) double wg64[DIM * NE];  // 32 KiB
  __shared__ float xt[256 * 33];  // 33 KiB, 256 tokens x 32-dim chunk, stride 33
  __shared__ int lcnt[NE];
  __shared__ int lbase[NE];
  __shared__ float limp[NE];
  __shared__ float lent;
  const int tid = threadIdx.x;
  const int tok0 = blockIdx.x * 256;

  for (int i = 0; i < 16; i++) {
    int idx = i * 256 + tid;
    wg64[idx] = (double)Wg[idx];
  }
  if (tid < NE) { lcnt[tid] = 0; limp[tid] = 0.f; }
  if (tid == NE) lent = 0.f;

  double acc[NE];
#pragma unroll
  for (int e = 0; e < NE; e++) acc[e] = (double)bg[e];

  for (int c = 0; c < 8; c++) {
    __syncthreads();  // also orders wg64/lcnt init before use
    const float* src = ctx + (size_t)tok0 * DIM + c * 32;
#pragma unroll
    for (int i = 0; i < 8; i++) {
      int f = i * 256 + tid;
      int row = f >> 3;
      int c4 = f & 7;
      float4 v = *(const float4*)(src + (size_t)row * DIM + c4 * 4);
      float* dstp = &xt[row * 33 + c4 * 4];
      dstp[0] = v.x; dstp[1] = v.y; dstp[2] = v.z; dstp[3] = v.w;
    }
    __syncthreads();
#pragma unroll
    for (int d = 0; d < 32; d++) {
      double x = (double)xt[tid * 33 + d];
      const double* wrow = &wg64[(c * 32 + d) * NE];
#pragma unroll
      for (int ee = 0; ee < 4; ee++) {  // double4 -> ds_read_b128 pairs
        doublex4 wv = *(const doublex4*)(wrow + ee * 4);
        acc[ee * 4 + 0] = fma(x, wv[0], acc[ee * 4 + 0]);
        acc[ee * 4 + 1] = fma(x, wv[1], acc[ee * 4 + 1]);
        acc[ee * 4 + 2] = fma(x, wv[2], acc[ee * 4 + 2]);
        acc[ee * 4 + 3] = fma(x, wv[3], acc[ee * 4 + 3]);
      }
    }
  }

  // top-2 (strict >: ties keep lowest index, matches lax.top_k)
  double v1 = -1e300, v2 = -1e300;
  int i1 = 0, i2 = 0;
#pragma unroll
  for (int e = 0; e < NE; e++) {
    double v = acc[e];
    if (v > v1) { v2 = v1; i2 = i1; v1 = v; i1 = e; }
    else if (v > v2) { v2 = v; i2 = e; }
  }

  // softmax probs (f32: feeds only importance/entropy)
  float p[NE];
  float s = 0.f;
#pragma unroll
  for (int e = 0; e < NE; e++) { p[e] = expf((float)(acc[e] - v1)); s += p[e]; }
  float inv_s = 1.f / s;
  float entl = 0.f;
#pragma unroll
  for (int e = 0; e < NE; e++) {
    float pe = p[e] * inv_s; p[e] = pe;
    entl -= pe * logf(fmaxf(pe, 1e-9f));
  }

  // gate scores: softmax over top-2 values, fp64
  double rr = exp(v2 - v1);
  double den = 1.0 + rr;
  float g1 = (float)(1.0 / den);
  float g2 = (float)(rr / den);

  // ---- hierarchical slot assignment ----
  int p1 = atomicAdd(&lcnt[i1], 1);  // LDS atomic: block-local rank
  int p2 = atomicAdd(&lcnt[i2], 1);
  __syncthreads();
  if (tid < NE) lbase[tid] = atomicAdd(&cnt[tid * 16], lcnt[tid]);  // padded lines
  __syncthreads();

  int token = tok0 + tid;
  int pos = lbase[i1] + p1;
  int l1 = -1;
  if (pos < CAP) { tok_list[i1 * CAP + pos] = token; sc_list[i1 * CAP + pos] = g1; l1 = i1 * CAP + pos; }
  pos = lbase[i2] + p2;
  int l2 = -1;
  if (pos < CAP) { tok_list[i2 * CAP + pos] = token; sc_list[i2 * CAP + pos] = g2; l2 = i2 * CAP + pos; }
  inv[token * 2] = l1;
  inv[token * 2 + 1] = l2;

  // ---- stats: wave shuffle-reduce -> LDS -> one global atomic per expert/block ----
#pragma unroll
  for (int e = 0; e < NE; e++) {
    float v = p[e];
#pragma unroll
    for (int o = 32; o > 0; o >>= 1) v += __shfl_down(v, o);
    if ((tid & 63) == 0) atomicAdd(&limp[e], v);
  }
  {
    float v = entl;
#pragma unroll
    for (int o = 32; o > 0; o >>= 1) v += __shfl_down(v, o);
    if ((tid & 63) == 0) atomicAdd(&lent, v);
  }
  __syncthreads();
  if (tid < NE) atomicAdd(&imp[tid * 16], limp[tid]);
  if (tid == NE) atomicAdd(ent, lent);
}

// ---------------- fused 2-layer expert MLP, 64-slot tile, bf16 MFMA ----------------
// 512 threads / 8 waves per block. LDS ~70 KB -> 2 blocks/CU -> 16 waves/CU
// (4/SIMD), double the latency-hiding of the 256-thread version at identical
// L2 weight traffic (weights read once per block per k-step, split over waves).
#define XB_STRIDE 264  // 256 + 8 bf16 pad
#define HB_STRIDE 520  // 512 + 8

template <bool GATHER>
__launch_bounds__(512, 4)
__global__ void k_expert(const float* __restrict__ ctx,
                         const bf16_t* __restrict__ W1T, const float* __restrict__ b1,
                         const bf16_t* __restrict__ W2T, const float* __restrict__ b2,
                         const int* __restrict__ cnt,
                         const int* __restrict__ tok_list, const float* __restrict__ sc_list,
                         bf16_t* __restrict__ y_buf, float* __restrict__ out) {
  // xb [64][264] bf16 aliases hb [64][520] bf16 aliases yb [64][264]
  __shared__ __align__(16) char smem_raw[64 * HB_STRIDE * 2];
  __shared__ int tok_s[64];
  __shared__ float sc_s[64];
  __shared__ float b1s[HID];
  __shared__ float b2s[DIM];
  bf16_t* xb = (bf16_t*)smem_raw;
  bf16_t* hb = (bf16_t*)smem_raw;
  bf16_t* yb = (bf16_t*)smem_raw;

  // XCD swizzle: bid%8 -> XCD; each XCD serves experts {2x,2x+1} -> 1MB weights/L2
  const int bid = blockIdx.x;
  const int e = (bid & 7) * 2 + ((bid >> 3) & 1);
  const int chunk = bid >> 4;

  const int count = min(cnt[e * 16], CAP);
  const int m0 = chunk * 64;
  if (m0 >= count) return;  // uniform early-exit, before any barrier
  const int rem = min(64, count - m0);

  const int tid = threadIdx.x;
  const int lane = tid & 63;
  const int w = tid >> 6;       // wave 0..7
  const int L15 = lane & 15;
  const int quad = (lane >> 4) & 3;

  if (tid < 64) {
    int t = 0; float sgate = 0.f;  // padded slots: token 0, gate 0
    if (tid < rem) {
      t = tok_list[e * CAP + m0 + tid];
      sgate = sc_list[e * CAP + m0 + tid];
    }
    tok_s[tid] = t; sc_s[tid] = sgate;
  }
  if (tid < HID) b1s[tid] = b1[e * HID + tid];
  if (tid < DIM) b2s[tid] = b2[e * DIM + tid];
  __syncthreads();

  // gather x: one full 1KB context row per wave-instr (coalesced), cast bf16
#pragma unroll
  for (int i = 0; i < 8; i++) {
    int row = i * 8 + w;  // wave-uniform
    float4 v = *(const float4*)(ctx + (size_t)tok_s[row] * DIM + lane * 4);
    bf16x4 bv;
    bv[0] = (bf16_t)v.x; bv[1] = (bf16_t)v.y; bv[2] = (bf16_t)v.z; bv[3] = (bf16_t)v.w;
    *(bf16x4*)(xb + row * XB_STRIDE + lane * 4) = bv;
  }
  __syncthreads();

  // ---- GEMM1': hT[n][m] = sum_k W1T[n][k]*x[m][k]; wave w owns n in [w*64, w*64+64)
  floatx4 acc1[4][4];
#pragma unroll
  for (int it = 0; it < 4; it++)
#pragma unroll
    for (int jt = 0; jt < 4; jt++) {
      floatx4 z = {0.f, 0.f, 0.f, 0.f};
      acc1[it][jt] = z;
    }

  const bf16_t* w1e = W1T + (size_t)e * HID * DIM;
#pragma unroll
  for (int k = 0; k < 8; k++) {
    bf16x8 afr[4];
#pragma unroll
    for (int it = 0; it < 4; it++) {
      int n = w * 64 + it * 16 + L15;
      afr[it] = *(const bf16x8*)(w1e + n * DIM + k * 32 + quad * 8);
    }
    bf16x8 bfr[4];
#pragma unroll
    for (int jt = 0; jt < 4; jt++) {
      int m = jt * 16 + L15;
      bfr[jt] = *(const bf16x8*)(xb + m * XB_STRIDE + k * 32 + quad * 8);
    }
#pragma unroll
    for (int it = 0; it < 4; it++)
#pragma unroll
      for (int jt = 0; jt < 4; jt++)
        acc1[it][jt] = __builtin_amdgcn_mfma_f32_16x16x32_bf16(afr[it], bfr[jt],
                                                               acc1[it][jt], 0, 0, 0);
  }
  __syncthreads();  // xb dead; hb may overwrite

  // epilogue 1: bias+relu, hT -> h[m][n] in LDS (A-operand-ready for GEMM2)
#pragma unroll
  for (int it = 0; it < 4; it++) {
    int n0 = w * 64 + it * 16 + quad * 4;
    float4 bb = *(const float4*)(&b1s[n0]);
#pragma unroll
    for (int jt = 0; jt < 4; jt++) {
      int m = jt * 16 + L15;
      bf16x4 hv;
      hv[0] = (bf16_t)fmaxf(acc1[it][jt][0] + bb.x, 0.f);
      hv[1] = (bf16_t)fmaxf(acc1[it][jt][1] + bb.y, 0.f);
      hv[2] = (bf16_t)fmaxf(acc1[it][jt][2] + bb.z, 0.f);
      hv[3] = (bf16_t)fmaxf(acc1[it][jt][3] + bb.w, 0.f);
      *(bf16x4*)(hb + m * HB_STRIDE + n0) = hv;
    }
  }
  __syncthreads();

  // ---- GEMM2: y[m][d] = sum_h h[m][h]*W2T[d][h]; wave w owns d in [w*32, w*32+32)
  floatx4 acc2[4][2];
#pragma unroll
  for (int mt = 0; mt < 4; mt++)
#pragma unroll
    for (int dt = 0; dt < 2; dt++) {
      floatx4 z = {0.f, 0.f, 0.f, 0.f};
      acc2[mt][dt] = z;
    }

  const bf16_t* w2e = W2T + (size_t)e * DIM * HID;
#pragma unroll
  for (int k = 0; k < 16; k++) {
    bf16x8 afr[4];
#pragma unroll
    for (int mt = 0; mt < 4; mt++)
      afr[mt] = *(const bf16x8*)(hb + (mt * 16 + L15) * HB_STRIDE + k * 32 + quad * 8);
    bf16x8 bfr[2];
#pragma unroll
    for (int dt = 0; dt < 2; dt++) {
      int d = w * 32 + dt * 16 + L15;
      bfr[dt] = *(const bf16x8*)(w2e + d * HID + k * 32 + quad * 8);
    }
#pragma unroll
    for (int mt = 0; mt < 4; mt++)
#pragma unroll
      for (int dt = 0; dt < 2; dt++)
        acc2[mt][dt] = __builtin_amdgcn_mfma_f32_16x16x32_bf16(afr[mt], bfr[dt],
                                                               acc2[mt][dt], 0, 0, 0);
  }

  if (GATHER) {
    // epilogue 2a: bias + gate-scale -> bf16 yb[m][d] in LDS, then coalesced
    // 512B row stores into y_buf (no atomics; combine kernel gathers later).
    __syncthreads();  // hb reads done; yb aliases
#pragma unroll
    for (int mt = 0; mt < 4; mt++) {
#pragma unroll
      for (int r = 0; r < 4; r++) {
        int m = mt * 16 + quad * 4 + r;
        float sg = sc_s[m];
#pragma unroll
        for (int dt = 0; dt < 2; dt++) {
          int d = w * 32 + dt * 16 + L15;
          yb[m * XB_STRIDE + d] = (bf16_t)((acc2[mt][dt][r] + b2s[d]) * sg);
        }
      }
    }
    __syncthreads();
    bf16_t* ybase = y_buf + ((size_t)e * CAP + m0) * DIM;
#pragma unroll
    for (int i = 0; i < 8; i++) {
      int row = i * 8 + w;  // wave-uniform
      if (row < rem) {      // never write past count -> no cross-expert clobber
        bf16x4 v = *(const bf16x4*)(yb + row * XB_STRIDE + lane * 4);
        *(bf16x4*)(ybase + (size_t)row * DIM + lane * 4) = v;
      }
    }
  } else {
    // epilogue 2b (fallback): atomic scatter-add
#pragma unroll
    for (int mt = 0; mt < 4; mt++) {
#pragma unroll
      for (int r = 0; r < 4; r++) {
        int m = mt * 16 + quad * 4 + r;
        int t = tok_s[m];
        float sg = sc_s[m];
        float* orow = out + (size_t)t * DIM;
#pragma unroll
        for (int dt = 0; dt < 2; dt++) {
          int d = w * 32 + dt * 16 + L15;
          float v = (acc2[mt][dt][r] + b2s[d]) * sg;
          atomicAdd(orow + d, v);
        }
      }
    }
  }
}

// ---------------- combine: per token, gather 2 slot rows, sum, write ----------------
__global__ void k_combine(const bf16_t* __restrict__ y_buf, const int* __restrict__ inv,
                          float* __restrict__ out) {
  __shared__ int loc_s[128];
  const int tid = threadIdx.x;
  const int tok0 = blockIdx.x * 64;
  if (tid < 128) loc_s[tid] = inv[tok0 * 2 + tid];
  __syncthreads();
  const int w = tid >> 6;
  const int lane = tid & 63;
#pragma unroll
  for (int i = 0; i < 16; i++) {
    int row = i * 4 + w;  // wave-uniform
    int l1 = loc_s[row * 2];
    int l2 = loc_s[row * 2 + 1];
    float4 o = make_float4(0.f, 0.f, 0.f, 0.f);
    if (l1 >= 0) {
      bf16x4 a = *(const bf16x4*)(y_buf + (size_t)l1 * DIM + lane * 4);
      o.x += (float)a[0]; o.y += (float)a[1]; o.z += (float)a[2]; o.w += (float)a[3];
    }
    if (l2 >= 0) {
      bf16x4 b = *(const bf16x4*)(y_buf + (size_t)l2 * DIM + lane * 4);
      o.x += (float)b[0]; o.y += (float)b[1]; o.z += (float)b[2]; o.w += (float)b[3];
    }
    *(float4*)(out + (size_t)(tok0 + row) * DIM + lane * 4) = o;
  }
}

// ---------------- aux stats ----------------
__global__ void k_finalize(const int* __restrict__ cnt, const float* __restrict__ imp,
                           const float* __restrict__ ent, float* __restrict__ out) {
  if (threadIdx.x == 0 && blockIdx.x == 0) {
    double tot = 0.0;
    float disp[NE];
    for (int e = 0; e < NE; e++) {
      int c = min(cnt[e * 16], CAP);
      disp[e] = (float)c;
      tot += (double)c;
    }
    double denom = tot > 0.0 ? tot : 1.0;
    double aux = 0.0;
    for (int e = 0; e < NE; e++)
      aux += ((double)imp[e * 16] / (double)N_TOK) * ((double)disp[e] / denom);
    float* tail = out + (size_t)N_TOK * DIM;
    tail[0] = (float)(aux * (double)NE);
    tail[1] = (float)((double)ent[0] / (double)N_TOK);
    for (int e = 0; e < NE; e++) tail[2 + e] = disp[e];
  }
}

extern "C" void kernel_launch(void* const* d_in, const int* in_sizes, int n_in,
                              void* d_out, int out_size, void* d_ws, size_t ws_size,
                              hipStream_t stream) {
  const float* ctx = (const float*)d_in[0];
  const float* Wg = (const float*)d_in[1];
  const float* bg = (const float*)d_in[2];
  const float* W1 = (const float*)d_in[3];
  const float* b1 = (const float*)d_in[4];
  const float* W2 = (const float*)d_in[5];
  const float* b2 = (const float*)d_in[6];
  float* out = (float*)d_out;
  char* ws = (char*)d_ws;

  int* cnt = (int*)(ws + OFF_CNT);
  float* imp = (float*)(ws + OFF_IMP);
  float* ent = (float*)(ws + OFF_ENT);
  int* tok_list = (int*)(ws + OFF_TOK);
  float* sc_list = (float*)(ws + OFF_SC);
  bf16_t* W1T = (bf16_t*)(ws + OFF_W1T);
  bf16_t* W2T = (bf16_t*)(ws + OFF_W2T);
  int* inv = (int*)(ws + OFF_INV);
  bf16_t* y_buf = (bf16_t*)(ws + OFF_Y);

  const bool gather = ws_size >= WS_NEED;  // constant across calls: graph-safe

  k_init<<<1, 64, 0, stream>>>(cnt, imp, ent);
  if (!gather) k_zero_out<<<2048, 256, 0, stream>>>(out);
  k_transpose<<<dim3(HID / 32, DIM / 32, NE), dim3(32, 8), 0, stream>>>(W1, W1T, DIM, HID);
  k_transpose<<<dim3(DIM / 32, HID / 32, NE), dim3(32, 8), 0, stream>>>(W2, W2T, HID, DIM);
  k_router<<<N_TOK / 256, 256, 0, stream>>>(ctx, Wg, bg, cnt, tok_list, sc_list, inv, imp, ent);
  // 16 experts x 282 chunks of 64 slots, xcd-swizzled; 512 threads = 8 waves/block
  if (gather) {
    k_expert<true><<<4512, 512, 0, stream>>>(ctx, W1T, b1, W2T, b2, cnt, tok_list, sc_list,
                                             y_buf, out);
    k_combine<<<N_TOK / 64, 256, 0, stream>>>(y_buf, inv, out);
  } else {
    k_expert<false><<<4512, 512, 0, stream>>>(ctx, W1T, b1, W2T, b2, cnt, tok_list, sc_list,
                                              y_buf, out);
  }
  k_finalize<<<1, 64, 0, stream>>>(cnt, imp, ent, out);
}

// Round 3
// 519.579 us; speedup vs baseline: 1.2093x; 1.1797x over previous
//
#include <hip/hip_runtime.h>
#include <hip/hip_bf16.h>
#include <math.h>

#define N_TOK 131072
#define DIM 256
#define HID 512
#define NE 16
#define CAP 18023

typedef __bf16 bf16_t;
typedef __bf16 bf16x4 __attribute__((ext_vector_type(4)));
typedef __bf16 bf16x8 __attribute__((ext_vector_type(8)));
typedef float floatx4 __attribute__((ext_vector_type(4)));
typedef double doublex4 __attribute__((ext_vector_type(4)));

// ---------------------------------------------------------------------------
// Workspace layout (bytes):
//   0        : int   cnt[16*16]   (one counter per 64B line: cnt[e*16])
//   1024     : float imp[16*16]   (padded: imp[e*16])
//   2048     : float ent[1]
//   4096     : int   tok_list[16*CAP] (1153472 B)
//   1157568  : float sc_list[16*CAP]  (1153472 B)
//   2311168  : bf16  W1F[16][32][8][64][8] (4 MiB)  MFMA-fragment-packed W1
//   6505472  : bf16  W2F[16][16][16][64][8] (4 MiB) MFMA-fragment-packed W2
//   10699776 : int   inv[N][2]  (1 MiB)  slot id e*CAP+pos per pick, -1 if dropped
//   11748352 : bf16  y_buf[16][CAP][256] (147.6 MB)  gate-scaled expert outputs
// total ~152 MB. If ws_size is smaller, fall back to atomic combine.
// ---------------------------------------------------------------------------
#define OFF_CNT 0
#define OFF_IMP 1024
#define OFF_ENT 2048
#define OFF_TOK 4096
#define OFF_SC 1157568
#define OFF_W1T 2311168
#define OFF_W2T 6505472
#define OFF_INV 10699776
#define OFF_Y 11748352
#define WS_NEED (11748352UL + (size_t)NE * CAP * DIM * 2)

// ---------------- init stats (gather path: no output zeroing needed) ----------------
__global__ void k_init(int* __restrict__ cnt, float* __restrict__ imp,
                       float* __restrict__ ent) {
  if (threadIdx.x < NE) { cnt[threadIdx.x * 16] = 0; imp[threadIdx.x * 16] = 0.f; }
  if (threadIdx.x == NE) ent[0] = 0.f;
}

// ---------------- zero output (atomic-fallback path only) ----------------
__global__ void k_zero_out(float* __restrict__ out) {
  const int nthreads = 2048 * 256;
  int tid = blockIdx.x * 256 + threadIdx.x;
  float4* o4 = (float4*)out;
  float4 z = make_float4(0.f, 0.f, 0.f, 0.f);
#pragma unroll
  for (int j = 0; j < 16; j++) o4[(size_t)j * nthreads + tid] = z;
}

// ---------------- weight packing: f32 [E][R][C] -> MFMA-fragment bf16 ----------------
// W1 [E][256=k][512=n] -> W1F frag(T=n/16, kk=k/32): value(lane,j) =
//   W1[e][kk*32 + (lane>>4)*8 + j][T*16 + (lane&15)]
// so k_expert's A-fragment load is base + lane*16B (contiguous 1KB per wave).
__global__ void k_pack1(const float* __restrict__ W1, bf16_t* __restrict__ W1F) {
  const int e = blockIdx.x;
  const int T = blockIdx.y;             // 0..31 (n-tile)
  const int l = threadIdx.x & 63;
  const int v = threadIdx.x >> 6;       // wave 0..3
  const float* src = W1 + (size_t)e * DIM * HID;
  bf16_t* dst = W1F + (size_t)e * HID * DIM;
  const int q8 = (l >> 4) * 8;
  const int c = T * 16 + (l & 15);
#pragma unroll
  for (int s = 0; s < 2; s++) {
    int kk = v + s * 4;                 // 0..7 (k-step of 32)
    bf16x8 fr;
#pragma unroll
    for (int j = 0; j < 8; j++)
      fr[j] = (bf16_t)src[(size_t)(kk * 32 + q8 + j) * HID + c];
    *(bf16x8*)(dst + ((size_t)(T * 8 + kk) * 64 + l) * 8) = fr;
  }
}

// W2 [E][512=h(k)][256=d] -> W2F frag(D=d/16, kk=h/32)
__global__ void k_pack2(const float* __restrict__ W2, bf16_t* __restrict__ W2F) {
  const int e = blockIdx.x;
  const int D = blockIdx.y;             // 0..15 (d-tile)
  const int l = threadIdx.x & 63;
  const int v = threadIdx.x >> 6;
  const float* src = W2 + (size_t)e * HID * DIM;
  bf16_t* dst = W2F + (size_t)e * DIM * HID;
  const int q8 = (l >> 4) * 8;
  const int c = D * 16 + (l & 15);
#pragma unroll
  for (int s = 0; s < 4; s++) {
    int kk = v + s * 4;                 // 0..15 (k-step of 32 over h)
    bf16x8 fr;
#pragma unroll
    for (int j = 0; j < 8; j++)
      fr[j] = (bf16_t)src[(size_t)(kk * 32 + q8 + j) * DIM + c];
    *(bf16x8*)(dst + ((size_t)(D * 16 + kk) * 64 + l) * 8) = fr;
  }
}

// ---------------- router: fp64 logits, top-2, gates, stats, inverse map ----------------
__launch_bounds__(256, 2)
__global__ void k_router(const float* __restrict__ ctx, const float* __restrict__ Wg,
                         const float* __restrict__ bg, int* __restrict__ cnt,
                         int* __restrict__ tok_list, float* __restrict__ sc_list,
                         int* __restrict__ inv,
                         float* __restrict__ imp, float* __restrict__ ent) {
  __shared__ __align__(32) double wg64[DIM * NE];  // 32 KiB
  __shared__ float xt[256 * 33];  // 33 KiB, 256 tokens x 32-dim chunk, stride 33
  __shared__ int lcnt[NE];
  __shared__ int lbase[NE];
  __shared__ float limp[NE];
  __shared__ float lent;
  const int tid = threadIdx.x;
  const int tok0 = blockIdx.x * 256;

  for (int i = 0; i < 16; i++) {
    int idx = i * 256 + tid;
    wg64[idx] = (double)Wg[idx];
  }
  if (tid < NE) { lcnt[tid] = 0; limp[tid] = 0.f; }
  if (tid == NE) lent = 0.f;

  double acc[NE];
#pragma unroll
  for (int e = 0; e < NE; e++) acc[e] = (double)bg[e];

  for (int c = 0; c < 8; c++) {
    __syncthreads();  // also orders wg64/lcnt init before use
    const float* src = ctx + (size_t)tok0 * DIM + c * 32;
#pragma unroll
    for (int i = 0; i < 8; i++) {
      int f = i * 256 + tid;
      int row = f >> 3;
      int c4 = f & 7;
      float4 v = *(const float4*)(src + (size_t)row * DIM + c4 * 4);
      float* dstp = &xt[row * 33 + c4 * 4];
      dstp[0] = v.x; dstp[1] = v.y; dstp[2] = v.z; dstp[3] = v.w;
    }
    __syncthreads();
#pragma unroll
    for (int d = 0; d < 32; d++) {
      double x = (double)xt[tid * 33 + d];
      const double* wrow = &wg64[(c * 32 + d) * NE];
#pragma unroll
      for (int ee = 0; ee < 4; ee++) {  // double4 -> ds_read_b128 pairs
        doublex4 wv = *(const doublex4*)(wrow + ee * 4);
        acc[ee * 4 + 0] = fma(x, wv[0], acc[ee * 4 + 0]);
        acc[ee * 4 + 1] = fma(x, wv[1], acc[ee * 4 + 1]);
        acc[ee * 4 + 2] = fma(x, wv[2], acc[ee * 4 + 2]);
        acc[ee * 4 + 3] = fma(x, wv[3], acc[ee * 4 + 3]);
      }
    }
  }

  // top-2 (strict >: ties keep lowest index, matches lax.top_k)
  double v1 = -1e300, v2 = -1e300;
  int i1 = 0, i2 = 0;
#pragma unroll
  for (int e = 0; e < NE; e++) {
    double v = acc[e];
    if (v > v1) { v2 = v1; i2 = i1; v1 = v; i1 = e; }
    else if (v > v2) { v2 = v; i2 = e; }
  }

  // softmax probs (f32: feeds only importance/entropy)
  float p[NE];
  float s = 0.f;
#pragma unroll
  for (int e = 0; e < NE; e++) { p[e] = expf((float)(acc[e] - v1)); s += p[e]; }
  float inv_s = 1.f / s;
  float entl = 0.f;
#pragma unroll
  for (int e = 0; e < NE; e++) {
    float pe = p[e] * inv_s; p[e] = pe;
    entl -= pe * logf(fmaxf(pe, 1e-9f));
  }

  // gate scores: softmax over top-2 values, fp64
  double rr = exp(v2 - v1);
  double den = 1.0 + rr;
  float g1 = (float)(1.0 / den);
  float g2 = (float)(rr / den);

  // ---- hierarchical slot assignment ----
  int p1 = atomicAdd(&lcnt[i1], 1);  // LDS atomic: block-local rank
  int p2 = atomicAdd(&lcnt[i2], 1);
  __syncthreads();
  if (tid < NE) lbase[tid] = atomicAdd(&cnt[tid * 16], lcnt[tid]);  // padded lines
  __syncthreads();

  int token = tok0 + tid;
  int pos = lbase[i1] + p1;
  int l1 = -1;
  if (pos < CAP) { tok_list[i1 * CAP + pos] = token; sc_list[i1 * CAP + pos] = g1; l1 = i1 * CAP + pos; }
  pos = lbase[i2] + p2;
  int l2 = -1;
  if (pos < CAP) { tok_list[i2 * CAP + pos] = token; sc_list[i2 * CAP + pos] = g2; l2 = i2 * CAP + pos; }
  inv[token * 2] = l1;
  inv[token * 2 + 1] = l2;

  // ---- stats: wave shuffle-reduce -> LDS -> one global atomic per expert/block ----
#pragma unroll
  for (int e = 0; e < NE; e++) {
    float v = p[e];
#pragma unroll
    for (int o = 32; o > 0; o >>= 1) v += __shfl_down(v, o);
    if ((tid & 63) == 0) atomicAdd(&limp[e], v);
  }
  {
    float v = entl;
#pragma unroll
    for (int o = 32; o > 0; o >>= 1) v += __shfl_down(v, o);
    if ((tid & 63) == 0) atomicAdd(&lent, v);
  }
  __syncthreads();
  if (tid < NE) atomicAdd(&imp[tid * 16], limp[tid]);
  if (tid == NE) atomicAdd(ent, lent);
}

// ---------------- fused 2-layer expert MLP, 64-slot tile, bf16 MFMA ----------------
// 512 threads / 8 waves, 2 blocks/CU. Weights loaded from fragment-packed
// layout (contiguous 1KB wave-loads) with explicit 1-deep register ping-pong
// prefetch across k-steps and across the epi1 barriers.
#define XB_STRIDE 264  // 256 + 8 bf16 pad
#define HB_STRIDE 520  // 512 + 8

#define MFMA_BF16 __builtin_amdgcn_mfma_f32_16x16x32_bf16

template <bool GATHER>
__launch_bounds__(512, 4)
__global__ void k_expert(const float* __restrict__ ctx,
                         const bf16_t* __restrict__ W1F, const float* __restrict__ b1,
                         const bf16_t* __restrict__ W2F, const float* __restrict__ b2,
                         const int* __restrict__ cnt,
                         const int* __restrict__ tok_list, const float* __restrict__ sc_list,
                         bf16_t* __restrict__ y_buf, float* __restrict__ out) {
  // xb [64][264] bf16 aliases hb [64][520] bf16 aliases yb [64][264]
  __shared__ __align__(16) char smem_raw[64 * HB_STRIDE * 2];
  __shared__ int tok_s[64];
  __shared__ float sc_s[64];
  __shared__ float b1s[HID];
  __shared__ float b2s[DIM];
  bf16_t* xb = (bf16_t*)smem_raw;
  bf16_t* hb = (bf16_t*)smem_raw;
  bf16_t* yb = (bf16_t*)smem_raw;

  // XCD swizzle: bid%8 -> XCD; each XCD serves experts {2x,2x+1} -> 1MB weights/L2
  const int bid = blockIdx.x;
  const int e = (bid & 7) * 2 + ((bid >> 3) & 1);
  const int chunk = bid >> 4;

  const int count = min(cnt[e * 16], CAP);
  const int m0 = chunk * 64;
  if (m0 >= count) return;  // uniform early-exit, before any barrier
  const int rem = min(64, count - m0);

  const int tid = threadIdx.x;
  const int lane = tid & 63;
  const int w = tid >> 6;       // wave 0..7
  const int L15 = lane & 15;
  const int quad = (lane >> 4) & 3;

  const bf16_t* w1f = W1F + (size_t)e * HID * DIM;
  const bf16_t* w2f = W2F + (size_t)e * DIM * HID;
#define LDW1(it, kk) (*(const bf16x8*)(w1f + (((w * 4 + (it)) * 8 + (kk)) * 64 + lane) * 8))
#define LDW2(dt, kk) (*(const bf16x8*)(w2f + (((w * 2 + (dt)) * 16 + (kk)) * 64 + lane) * 8))

  // issue GEMM1 k=0 weight fragments immediately (depend only on e)
  bf16x8 wA0 = LDW1(0, 0), wA1 = LDW1(1, 0), wA2 = LDW1(2, 0), wA3 = LDW1(3, 0);
  bf16x8 wB0, wB1, wB2, wB3;

  // wave-local token fetch for this wave's gather rows (no LDS, no barrier)
  int tval = 0; float sval = 0.f;
  if (lane < 8) {
    int r = lane * 8 + w;
    if (r < rem) {
      tval = tok_list[e * CAP + m0 + r];
      sval = sc_list[e * CAP + m0 + r];
    }
  }
  // block-wide tables (consumed after later barriers; fallback + epi2 need them)
  if (tid < 64) {
    int t = 0; float sgate = 0.f;
    if (tid < rem) {
      t = tok_list[e * CAP + m0 + tid];
      sgate = sc_list[e * CAP + m0 + tid];
    }
    tok_s[tid] = t; sc_s[tid] = sgate;
  }
  b1s[tid] = b1[e * HID + tid];          // 512 threads == HID
  if (tid < DIM) b2s[tid] = b2[e * DIM + tid];

  // gather x: one full 1KB context row per wave-instr (coalesced), cast bf16
#pragma unroll
  for (int i = 0; i < 8; i++) {
    int row = i * 8 + w;  // wave-uniform
    int trow = __shfl(tval, i);
    float4 v = *(const float4*)(ctx + (size_t)trow * DIM + lane * 4);
    bf16x4 bv;
    bv[0] = (bf16_t)v.x; bv[1] = (bf16_t)v.y; bv[2] = (bf16_t)v.z; bv[3] = (bf16_t)v.w;
    *(bf16x4*)(xb + row * XB_STRIDE + lane * 4) = bv;
  }
  __syncthreads();

  // ---- GEMM1': hT[n][m] = sum_k W1T[n][k]*x[m][k]; wave w owns n in [w*64, w*64+64)
  floatx4 acc1[4][4];
#pragma unroll
  for (int it = 0; it < 4; it++)
#pragma unroll
    for (int jt = 0; jt < 4; jt++) {
      floatx4 z = {0.f, 0.f, 0.f, 0.f};
      acc1[it][jt] = z;
    }

#define G1ROW(i, CA) \
  acc1[i][0] = MFMA_BF16(CA, b0_, acc1[i][0], 0, 0, 0); \
  acc1[i][1] = MFMA_BF16(CA, b1_, acc1[i][1], 0, 0, 0); \
  acc1[i][2] = MFMA_BF16(CA, b2_, acc1[i][2], 0, 0, 0); \
  acc1[i][3] = MFMA_BF16(CA, b3_, acc1[i][3], 0, 0, 0);

#define G1STEP(kk, PRE, CA0, CA1, CA2, CA3, CN0, CN1, CN2, CN3) do {            \
    bf16x8 b0_ = *(const bf16x8*)(xb + (0 * 16 + L15) * XB_STRIDE + (kk) * 32 + quad * 8); \
    bf16x8 b1_ = *(const bf16x8*)(xb + (1 * 16 + L15) * XB_STRIDE + (kk) * 32 + quad * 8); \
    bf16x8 b2_ = *(const bf16x8*)(xb + (2 * 16 + L15) * XB_STRIDE + (kk) * 32 + quad * 8); \
    bf16x8 b3_ = *(const bf16x8*)(xb + (3 * 16 + L15) * XB_STRIDE + (kk) * 32 + quad * 8); \
    if (PRE) { CN0 = LDW1(0, (kk) + 1); CN1 = LDW1(1, (kk) + 1);               \
               CN2 = LDW1(2, (kk) + 1); CN3 = LDW1(3, (kk) + 1); }             \
    G1ROW(0, CA0) G1ROW(1, CA1) G1ROW(2, CA2) G1ROW(3, CA3)                    \
  } while (0)

  G1STEP(0, 1, wA0, wA1, wA2, wA3, wB0, wB1, wB2, wB3);
  G1STEP(1, 1, wB0, wB1, wB2, wB3, wA0, wA1, wA2, wA3);
  G1STEP(2, 1, wA0, wA1, wA2, wA3, wB0, wB1, wB2, wB3);
  G1STEP(3, 1, wB0, wB1, wB2, wB3, wA0, wA1, wA2, wA3);
  G1STEP(4, 1, wA0, wA1, wA2, wA3, wB0, wB1, wB2, wB3);
  G1STEP(5, 1, wB0, wB1, wB2, wB3, wA0, wA1, wA2, wA3);
  G1STEP(6, 1, wA0, wA1, wA2, wA3, wB0, wB1, wB2, wB3);
  G1STEP(7, 0, wB0, wB1, wB2, wB3, wA0, wA1, wA2, wA3);

  // issue GEMM2 k=0 weight fragments now: in flight across the epi1 barriers
  bf16x8 c0a = LDW2(0, 0), c0b = LDW2(1, 0);
  bf16x8 c1a, c1b;

  __syncthreads();  // xb dead; hb may overwrite

  // epilogue 1: bias+relu, hT -> h[m][n] in LDS (A-operand-ready for GEMM2)
#pragma unroll
  for (int it = 0; it < 4; it++) {
    int n0 = w * 64 + it * 16 + quad * 4;
    float4 bb = *(const float4*)(&b1s[n0]);
#pragma unroll
    for (int jt = 0; jt < 4; jt++) {
      int m = jt * 16 + L15;
      bf16x4 hv;
      hv[0] = (bf16_t)fmaxf(acc1[it][jt][0] + bb.x, 0.f);
      hv[1] = (bf16_t)fmaxf(acc1[it][jt][1] + bb.y, 0.f);
      hv[2] = (bf16_t)fmaxf(acc1[it][jt][2] + bb.z, 0.f);
      hv[3] = (bf16_t)fmaxf(acc1[it][jt][3] + bb.w, 0.f);
      *(bf16x4*)(hb + m * HB_STRIDE + n0) = hv;
    }
  }
  __syncthreads();

  // ---- GEMM2: y[m][d] = sum_h h[m][h]*W2T[d][h]; wave w owns d in [w*32, w*32+32)
  floatx4 acc2[4][2];
#pragma unroll
  for (int mt = 0; mt < 4; mt++)
#pragma unroll
    for (int dt = 0; dt < 2; dt++) {
      floatx4 z = {0.f, 0.f, 0.f, 0.f};
      acc2[mt][dt] = z;
    }

#define G2STEP(kk, PRE, C0, C1, N0, N1) do {                                    \
    bf16x8 a0_ = *(const bf16x8*)(hb + (0 * 16 + L15) * HB_STRIDE + (kk) * 32 + quad * 8); \
    bf16x8 a1_ = *(const bf16x8*)(hb + (1 * 16 + L15) * HB_STRIDE + (kk) * 32 + quad * 8); \
    bf16x8 a2_ = *(const bf16x8*)(hb + (2 * 16 + L15) * HB_STRIDE + (kk) * 32 + quad * 8); \
    bf16x8 a3_ = *(const bf16x8*)(hb + (3 * 16 + L15) * HB_STRIDE + (kk) * 32 + quad * 8); \
    if (PRE) { N0 = LDW2(0, (kk) + 1); N1 = LDW2(1, (kk) + 1); }               \
    acc2[0][0] = MFMA_BF16(a0_, C0, acc2[0][0], 0, 0, 0);                      \
    acc2[0][1] = MFMA_BF16(a0_, C1, acc2[0][1], 0, 0, 0);                      \
    acc2[1][0] = MFMA_BF16(a1_, C0, acc2[1][0], 0, 0, 0);                      \
    acc2[1][1] = MFMA_BF16(a1_, C1, acc2[1][1], 0, 0, 0);                      \
    acc2[2][0] = MFMA_BF16(a2_, C0, acc2[2][0], 0, 0, 0);                      \
    acc2[2][1] = MFMA_BF16(a2_, C1, acc2[2][1], 0, 0, 0);                      \
    acc2[3][0] = MFMA_BF16(a3_, C0, acc2[3][0], 0, 0, 0);                      \
    acc2[3][1] = MFMA_BF16(a3_, C1, acc2[3][1], 0, 0, 0);                      \
  } while (0)

  G2STEP(0,  1, c0a, c0b, c1a, c1b);
  G2STEP(1,  1, c1a, c1b, c0a, c0b);
  G2STEP(2,  1, c0a, c0b, c1a, c1b);
  G2STEP(3,  1, c1a, c1b, c0a, c0b);
  G2STEP(4,  1, c0a, c0b, c1a, c1b);
  G2STEP(5,  1, c1a, c1b, c0a, c0b);
  G2STEP(6,  1, c0a, c0b, c1a, c1b);
  G2STEP(7,  1, c1a, c1b, c0a, c0b);
  G2STEP(8,  1, c0a, c0b, c1a, c1b);
  G2STEP(9,  1, c1a, c1b, c0a, c0b);
  G2STEP(10, 1, c0a, c0b, c1a, c1b);
  G2STEP(11, 1, c1a, c1b, c0a, c0b);
  G2STEP(12, 1, c0a, c0b, c1a, c1b);
  G2STEP(13, 1, c1a, c1b, c0a, c0b);
  G2STEP(14, 1, c0a, c0b, c1a, c1b);
  G2STEP(15, 0, c1a, c1b, c0a, c0b);

  if (GATHER) {
    // epilogue 2a: bias + gate-scale -> bf16 yb[m][d] in LDS, then coalesced
    // 512B row stores into y_buf (no atomics; combine kernel gathers later).
    __syncthreads();  // hb reads done; yb aliases
#pragma unroll
    for (int mt = 0; mt < 4; mt++) {
#pragma unroll
      for (int r = 0; r < 4; r++) {
        int m = mt * 16 + quad * 4 + r;
        float sg = sc_s[m];
#pragma unroll
        for (int dt = 0; dt < 2; dt++) {
          int d = w * 32 + dt * 16 + L15;
          yb[m * XB_STRIDE + d] = (bf16_t)((acc2[mt][dt][r] + b2s[d]) * sg);
        }
      }
    }
    __syncthreads();
    bf16_t* ybase = y_buf + ((size_t)e * CAP + m0) * DIM;
#pragma unroll
    for (int i = 0; i < 8; i++) {
      int row = i * 8 + w;  // wave-uniform
      if (row < rem) {      // never write past count -> no cross-expert clobber
        bf16x4 v = *(const bf16x4*)(yb + row * XB_STRIDE + lane * 4);
        *(bf16x4*)(ybase + (size_t)row * DIM + lane * 4) = v;
      }
    }
  } else {
    // epilogue 2b (fallback): atomic scatter-add
#pragma unroll
    for (int mt = 0; mt < 4; mt++) {
#pragma unroll
      for (int r = 0; r < 4; r++) {
        int m = mt * 16 + quad * 4 + r;
        int t = tok_s[m];
        float sg = sc_s[m];
        float* orow = out + (size_t)t * DIM;
#pragma unroll
        for (int dt = 0; dt < 2; dt++) {
          int d = w * 32 + dt * 16 + L15;
          float v = (acc2[mt][dt][r] + b2s[d]) * sg;
          atomicAdd(orow + d, v);
        }
      }
    }
  }
}

// ---------------- combine: per token, gather 2 slot rows, sum, write ----------------
__global__ void k_combine(const bf16_t* __restrict__ y_buf, const int* __restrict__ inv,
                          float* __restrict__ out) {
  __shared__ int loc_s[128];
  const int tid = threadIdx.x;
  const int tok0 = blockIdx.x * 64;
  if (tid < 128) loc_s[tid] = inv[tok0 * 2 + tid];
  __syncthreads();
  const int w = tid >> 6;
  const int lane = tid & 63;
#pragma unroll
  for (int i = 0; i < 16; i++) {
    int row = i * 4 + w;  // wave-uniform
    int l1 = loc_s[row * 2];
    int l2 = loc_s[row * 2 + 1];
    float4 o = make_float4(0.f, 0.f, 0.f, 0.f);
    if (l1 >= 0) {
      bf16x4 a = *(const bf16x4*)(y_buf + (size_t)l1 * DIM + lane * 4);
      o.x += (float)a[0]; o.y += (float)a[1]; o.z += (float)a[2]; o.w += (float)a[3];
    }
    if (l2 >= 0) {
      bf16x4 b = *(const bf16x4*)(y_buf + (size_t)l2 * DIM + lane * 4);
      o.x += (float)b[0]; o.y += (float)b[1]; o.z += (float)b[2]; o.w += (float)b[3];
    }
    *(float4*)(out + (size_t)(tok0 + row) * DIM + lane * 4) = o;
  }
}

// ---------------- aux stats ----------------
__global__ void k_finalize(const int* __restrict__ cnt, const float* __restrict__ imp,
                           const float* __restrict__ ent, float* __restrict__ out) {
  if (threadIdx.x == 0 && blockIdx.x == 0) {
    double tot = 0.0;
    float disp[NE];
    for (int e = 0; e < NE; e++) {
      int c = min(cnt[e * 16], CAP);
      disp[e] = (float)c;
      tot += (double)c;
    }
    double denom = tot > 0.0 ? tot : 1.0;
    double aux = 0.0;
    for (int e = 0; e < NE; e++)
      aux += ((double)imp[e * 16] / (double)N_TOK) * ((double)disp[e] / denom);
    float* tail = out + (size_t)N_TOK * DIM;
    tail[0] = (float)(aux * (double)NE);
    tail[1] = (float)((double)ent[0] / (double)N_TOK);
    for (int e = 0; e < NE; e++) tail[2 + e] = disp[e];
  }
}

extern "C" void kernel_launch(void* const* d_in, const int* in_sizes, int n_in,
                              void* d_out, int out_size, void* d_ws, size_t ws_size,
                              hipStream_t stream) {
  const float* ctx = (const float*)d_in[0];
  const float* Wg = (const float*)d_in[1];
  const float* bg = (const float*)d_in[2];
  const float* W1 = (const float*)d_in[3];
  const float* b1 = (const float*)d_in[4];
  const float* W2 = (const float*)d_in[5];
  const float* b2 = (const float*)d_in[6];
  float* out = (float*)d_out;
  char* ws = (char*)d_ws;

  int* cnt = (int*)(ws + OFF_CNT);
  float* imp = (float*)(ws + OFF_IMP);
  float* ent = (float*)(ws + OFF_ENT);
  int* tok_list = (int*)(ws + OFF_TOK);
  float* sc_list = (float*)(ws + OFF_SC);
  bf16_t* W1F = (bf16_t*)(ws + OFF_W1T);
  bf16_t* W2F = (bf16_t*)(ws + OFF_W2T);
  int* inv = (int*)(ws + OFF_INV);
  bf16_t* y_buf = (bf16_t*)(ws + OFF_Y);

  const bool gather = ws_size >= WS_NEED;  // constant across calls: graph-safe

  k_init<<<1, 64, 0, stream>>>(cnt, imp, ent);
  if (!gather) k_zero_out<<<2048, 256, 0, stream>>>(out);
  k_pack1<<<dim3(NE, 32), 256, 0, stream>>>(W1, W1F);
  k_pack2<<<dim3(NE, 16), 256, 0, stream>>>(W2, W2F);
  k_router<<<N_TOK / 256, 256, 0, stream>>>(ctx, Wg, bg, cnt, tok_list, sc_list, inv, imp, ent);
  // 16 experts x 282 chunks of 64 slots, xcd-swizzled; 512 threads = 8 waves/block
  if (gather) {
    k_expert<true><<<4512, 512, 0, stream>>>(ctx, W1F, b1, W2F, b2, cnt, tok_list, sc_list,
                                             y_buf, out);
    k_combine<<<N_TOK / 64, 256, 0, stream>>>(y_buf, inv, out);
  } else {
    k_expert<false><<<4512, 512, 0, stream>>>(ctx, W1F, b1, W2F, b2, cnt, tok_list, sc_list,
                                              y_buf, out);
  }
  k_finalize<<<1, 64, 0, stream>>>(cnt, imp, ent, out);
}